// Round 1
// baseline (207.619 us; speedup 1.0000x reference)
//
#include <hip/hip_runtime.h>
#include <stdint.h>

#define NLAYERS 6
#define DD      128   // patch dim
#define CONDD   128
#define HID     256
#define DIN     192   // 64 + 128
#define TM      64    // tokens per block
#define NTHR    512   // 8 waves

typedef __attribute__((ext_vector_type(4))) float f32x4;
typedef __attribute__((ext_vector_type(8))) short short8;

// packed-weight geometry (16x16x32 bf16 MFMA B-fragments)
#define G1_KS 6
#define G2_KS 8
#define G3_KS 8
#define G1_FR (G1_KS*16)             // 96 frags
#define G2_FR (G2_KS*16)             // 128
#define G3_FR (G3_KS*8)              // 64
#define FR_L  (G1_FR+G2_FR+G3_FR)    // 288 frags / layer
#define EL_L  (FR_L*512)             // 147456 bf16 elems / layer
#define G2_OFF (G1_FR*512)
#define G3_OFF ((G1_FR+G2_FR)*512)

__device__ __forceinline__ short f2bf(float f) {   // fp32 -> bf16 (RNE)
  uint32_t u = __builtin_bit_cast(uint32_t, f);
  u += 0x7fffu + ((u >> 16) & 1u);
  return (short)(u >> 16);
}

// Pack W[k][n] (fp32, row-major [in][out]) into per-fragment bf16 layout:
// frag (ks,nf): lane l holds B[k0+(l>>4)*8 + j][nf*16 + (l&15)], j=0..7 contiguous.
__global__ void prep_weights(const float* __restrict__ W1,
                             const float* __restrict__ W2,
                             const float* __restrict__ W3,
                             short* __restrict__ wp)
{
  int t = blockIdx.x * 256 + threadIdx.x;      // 6*288*64 = 110592 threads exactly
  int lay  = t / (FR_L * 64);
  int rem  = t - lay * (FR_L * 64);
  int frag = rem >> 6;
  int lane = rem & 63;
  const float* src;
  int N, f2, dstbase, nfr;
  if (frag < G1_FR) {
    f2 = frag;                  src = W1 + (size_t)lay * DIN * HID; N = HID; dstbase = 0;      nfr = 16;
  } else if (frag < G1_FR + G2_FR) {
    f2 = frag - G1_FR;          src = W2 + (size_t)lay * HID * HID; N = HID; dstbase = G2_OFF; nfr = 16;
  } else {
    f2 = frag - (G1_FR + G2_FR);src = W3 + (size_t)lay * HID * DD;  N = DD;  dstbase = G3_OFF; nfr = 8;
  }
  int ks = f2 / nfr, nf = f2 - ks * nfr;
  int n  = nf * 16 + (lane & 15);
  int k0 = ks * 32 + (lane >> 4) * 8;
  short8 v;
#pragma unroll
  for (int j = 0; j < 8; ++j) v[j] = f2bf(src[(size_t)(k0 + j) * N + n]);
  *(short8*)(wp + (size_t)lay * EL_L + dstbase + ((size_t)f2 * 64 + lane) * 8) = v;
}

__global__ __launch_bounds__(NTHR, 2)
void flow_kernel(const float* __restrict__ x, const float* __restrict__ cond,
                 const float* __restrict__ b1g, const float* __restrict__ b2g,
                 const float* __restrict__ b3g, const short* __restrict__ wp,
                 float* __restrict__ outz, float* __restrict__ outld)
{
  __shared__ alignas(16) short bufA[TM * DIN];   // [64][192] bf16: [x1 | cond], swizzled. 24KB
  __shared__ alignas(16) short bufB[TM * HID];   // h1 bf16 / st fp32 overlay.           32KB
  __shared__ alignas(16) short bufC[TM * HID];   // h2 bf16.                             32KB
  __shared__ alignas(16) float zb[TM * DD];      // z fp32 (exact passthrough).          32KB
  __shared__ float red[8];

  const int tid  = threadIdx.x;
  const int wave = tid >> 6;
  const int lane = tid & 63;
  const int l15  = lane & 15;
  const int l4   = lane >> 4;
  const int t0   = blockIdx.x * TM;
  const int batch = t0 >> 7;                 // 64 | 128 => one batch per block
  float* stf = (float*)bufB;                 // [64][128] fp32 st buffer (overlay)

  { // global x -> zb (fp32, coalesced float4)
    const f32x4* xs = (const f32x4*)(x + (size_t)t0 * DD);
    f32x4* zd = (f32x4*)zb;
#pragma unroll
    for (int j = 0; j < 4; ++j) zd[tid + NTHR * j] = xs[tid + NTHR * j];
  }
  // cond -> bufA cols 64..191 (bf16, once: never overwritten)
#pragma unroll
  for (int j = 0; j < 16; ++j) {
    int i = tid + NTHR * j;
    int m = i >> 7, c = i & 127;
    int off = ((m * DIN + 64 + c) * 2) ^ ((m & 7) << 4);
    *(short*)((char*)bufA + off) = f2bf(cond[batch * CONDD + c]);
  }

  float ldsum = 0.f;
  const f32x4 vzero = {0.f, 0.f, 0.f, 0.f};

  for (int lay = 0; lay < NLAYERS; ++lay) {
    const short* wl = wp + (size_t)lay * EL_L;
    __syncthreads();                         // zb (and bufA cond) visible
    // stage x1 = zb[:,0:64] -> bufA cols 0..63 (bf16)
#pragma unroll
    for (int j = 0; j < 8; ++j) {
      int i = tid + NTHR * j;
      int m = i >> 6, c = i & 63;
      int off = ((m * DIN + c) * 2) ^ ((m & 7) << 4);
      *(short*)((char*)bufA + off) = f2bf(zb[m * DD + c]);
    }
    __syncthreads();                         // bufA ready

    // ---- GEMM1: [64x192] @ W1[192x256] + b1, relu -> bufB ----
    {
      f32x4 acc[4][2];
#pragma unroll
      for (int mf = 0; mf < 4; ++mf) { acc[mf][0] = vzero; acc[mf][1] = vzero; }
#pragma unroll
      for (int ks = 0; ks < G1_KS; ++ks) {
        short8 a[4];
#pragma unroll
        for (int mf = 0; mf < 4; ++mf) {
          int row = mf * 16 + l15;
          int off = ((row * DIN + ks * 32 + l4 * 8) * 2) ^ ((row & 7) << 4);
          a[mf] = *(const short8*)((const char*)bufA + off);
        }
        short8 bb0 = *(const short8*)(wl + ((ks * 16 + wave * 2 + 0) * 64 + lane) * 8);
        short8 bb1 = *(const short8*)(wl + ((ks * 16 + wave * 2 + 1) * 64 + lane) * 8);
#pragma unroll
        for (int mf = 0; mf < 4; ++mf) {
          acc[mf][0] = __builtin_amdgcn_mfma_f32_16x16x32_bf16(a[mf], bb0, acc[mf][0], 0, 0, 0);
          acc[mf][1] = __builtin_amdgcn_mfma_f32_16x16x32_bf16(a[mf], bb1, acc[mf][1], 0, 0, 0);
        }
      }
#pragma unroll
      for (int nf = 0; nf < 2; ++nf) {
        int col = wave * 32 + nf * 16 + l15;
        float bias = b1g[lay * HID + col];
#pragma unroll
        for (int mf = 0; mf < 4; ++mf)
#pragma unroll
          for (int r = 0; r < 4; ++r) {
            int row = mf * 16 + l4 * 4 + r;
            float v = fmaxf(acc[mf][nf][r] + bias, 0.f);
            int off = ((row * HID + col) * 2) ^ ((row & 7) << 4);
            *(short*)((char*)bufB + off) = f2bf(v);
          }
      }
    }
    __syncthreads();                         // h1 ready

    // ---- GEMM2: bufB @ W2[256x256] + b2, relu -> bufC ----
    {
      const short* wg = wl + G2_OFF;
      f32x4 acc[4][2];
#pragma unroll
      for (int mf = 0; mf < 4; ++mf) { acc[mf][0] = vzero; acc[mf][1] = vzero; }
#pragma unroll
      for (int ks = 0; ks < G2_KS; ++ks) {
        short8 a[4];
#pragma unroll
        for (int mf = 0; mf < 4; ++mf) {
          int row = mf * 16 + l15;
          int off = ((row * HID + ks * 32 + l4 * 8) * 2) ^ ((row & 7) << 4);
          a[mf] = *(const short8*)((const char*)bufB + off);
        }
        short8 bb0 = *(const short8*)(wg + ((ks * 16 + wave * 2 + 0) * 64 + lane) * 8);
        short8 bb1 = *(const short8*)(wg + ((ks * 16 + wave * 2 + 1) * 64 + lane) * 8);
#pragma unroll
        for (int mf = 0; mf < 4; ++mf) {
          acc[mf][0] = __builtin_amdgcn_mfma_f32_16x16x32_bf16(a[mf], bb0, acc[mf][0], 0, 0, 0);
          acc[mf][1] = __builtin_amdgcn_mfma_f32_16x16x32_bf16(a[mf], bb1, acc[mf][1], 0, 0, 0);
        }
      }
#pragma unroll
      for (int nf = 0; nf < 2; ++nf) {
        int col = wave * 32 + nf * 16 + l15;
        float bias = b2g[lay * HID + col];
#pragma unroll
        for (int mf = 0; mf < 4; ++mf)
#pragma unroll
          for (int r = 0; r < 4; ++r) {
            int row = mf * 16 + l4 * 4 + r;
            float v = fmaxf(acc[mf][nf][r] + bias, 0.f);
            int off = ((row * HID + col) * 2) ^ ((row & 7) << 4);
            *(short*)((char*)bufC + off) = f2bf(v);
          }
      }
    }
    __syncthreads();                         // h2 ready (all GEMM2 bufB reads done)

    // ---- GEMM3: bufC @ W3[256x128] + b3 -> stf (fp32, overlays bufB) ----
    {
      f32x4 acc3[4];
#pragma unroll
      for (int mf = 0; mf < 4; ++mf) acc3[mf] = vzero;
#pragma unroll
      for (int ks = 0; ks < G3_KS; ++ks) {
        short8 a[4];
#pragma unroll
        for (int mf = 0; mf < 4; ++mf) {
          int row = mf * 16 + l15;
          int off = ((row * HID + ks * 32 + l4 * 8) * 2) ^ ((row & 7) << 4);
          a[mf] = *(const short8*)((const char*)bufC + off);
        }
        short8 bb = *(const short8*)(wl + G3_OFF + ((ks * 8 + wave) * 64 + lane) * 8);
#pragma unroll
        for (int mf = 0; mf < 4; ++mf)
          acc3[mf] = __builtin_amdgcn_mfma_f32_16x16x32_bf16(a[mf], bb, acc3[mf], 0, 0, 0);
      }
      int col = wave * 16 + l15;
      float bias = b3g[lay * DD + col];
#pragma unroll
      for (int mf = 0; mf < 4; ++mf)
#pragma unroll
        for (int r = 0; r < 4; ++r)
          stf[(mf * 16 + l4 * 4 + r) * DD + col] = acc3[mf][r] + bias;
    }
    __syncthreads();                         // st ready

    // ---- epilogue: coupling + flip (z stays fp32) ----
    float y2v[8], x1v[8];
#pragma unroll
    for (int j = 0; j < 8; ++j) {
      int q = tid + NTHR * j;
      int m = q >> 6, dd = q & 63;
      float sr = stf[m * DD + dd];
      sr = fminf(fmaxf(sr, -8.f), 8.f);
      float tt = stf[m * DD + 64 + dd];
      float e2 = __expf(2.f * sr);
      float s  = 0.5f * (e2 - 1.f) / (e2 + 1.f);   // 0.5*tanh(sr)
      ldsum += s;
      x1v[j] = zb[m * DD + dd];
      y2v[j] = fmaf(zb[m * DD + 64 + dd], __expf(s), tt);
    }
    __syncthreads();                         // all z/st reads done before z writes
#pragma unroll
    for (int j = 0; j < 8; ++j) {
      int q = tid + NTHR * j;
      int m = q >> 6, dd = q & 63;
      zb[m * DD + 63 - dd]  = y2v[j];        // z_new[63-dd]  = y2[dd]
      zb[m * DD + 127 - dd] = x1v[j];        // z_new[127-dd] = x1[dd]
    }
  }
  __syncthreads();

  { // store z
    const f32x4* zs = (const f32x4*)zb;
    f32x4* od = (f32x4*)(outz + (size_t)t0 * DD);
#pragma unroll
    for (int j = 0; j < 4; ++j) od[tid + NTHR * j] = zs[tid + NTHR * j];
  }
  // logdet: wave shuffle-reduce -> block -> one atomic (2 blocks/batch: commutative, deterministic)
#pragma unroll
  for (int off = 32; off > 0; off >>= 1) ldsum += __shfl_down(ldsum, off);
  if (lane == 0) red[wave] = ldsum;
  __syncthreads();
  if (tid == 0) {
    float s = 0.f;
#pragma unroll
    for (int w = 0; w < 8; ++w) s += red[w];
    atomicAdd(&outld[batch], s);
  }
}

extern "C" void kernel_launch(void* const* d_in, const int* in_sizes, int n_in,
                              void* d_out, int out_size, void* d_ws, size_t ws_size,
                              hipStream_t stream)
{
  (void)in_sizes; (void)n_in; (void)out_size; (void)ws_size;
  const float* x   = (const float*)d_in[0];
  const float* cnd = (const float*)d_in[1];
  const float* W1  = (const float*)d_in[2];
  const float* b1  = (const float*)d_in[3];
  const float* W2  = (const float*)d_in[4];
  const float* b2  = (const float*)d_in[5];
  const float* W3  = (const float*)d_in[6];
  const float* b3  = (const float*)d_in[7];
  float* outz  = (float*)d_out;
  float* outld = outz + (size_t)512 * 128 * 128;
  short* wp = (short*)d_ws;                  // 1.77 MB packed bf16 weights

  hipMemsetAsync(outld, 0, 512 * sizeof(float), stream);
  prep_weights<<<432, 256, 0, stream>>>(W1, W2, W3, wp);
  flow_kernel<<<1024, NTHR, 0, stream>>>(x, cnd, b1, b2, b3, wp, outz, outld);
}